// Round 15
// baseline (442.094 us; speedup 1.0000x reference)
//
#include <hip/hip_runtime.h>
#include <hip/hip_bf16.h>
#include <cstddef>
#include <cstdint>
#include <climits>

#define TOT_ANCH 25200

typedef __bf16 bf16x8 __attribute__((ext_vector_type(8)));
typedef float f32x4 __attribute__((ext_vector_type(4)));

__device__ __forceinline__ float sig_(float x) { return 1.0f / (1.0f + __expf(-x)); }

__device__ __forceinline__ short f2bf(float v) {
  return (short)__builtin_bit_cast(unsigned short, __float2bfloat16(v));
}
__device__ __forceinline__ float bf2f(short v) {
  unsigned int u = ((unsigned int)(unsigned short)v) << 16;
  return __builtin_bit_cast(float, u);
}
__device__ __forceinline__ bf16x8 as_bf16x8(int4 v) { return __builtin_bit_cast(bf16x8, v); }

__device__ __forceinline__ void gload_lds16(const void* g, void* l) {
  __builtin_amdgcn_global_load_lds((const __attribute__((address_space(1))) void*)g,
                                   (__attribute__((address_space(3))) void*)l, 16, 0, 0);
}

// anchors[level][a][2]
__device__ const float d_anch[3][3][2] = {
    {{10.f, 13.f}, {16.f, 30.f}, {33.f, 23.f}},
    {{30.f, 61.f}, {62.f, 45.f}, {59.f, 119.f}},
    {{116.f, 90.f}, {156.f, 198.f}, {373.f, 326.f}}};

// --------------------------- param structs (by value) -----------------------
struct TrP {  // f32 NCHW -> bf16 NHWC with 1-px halo: fb[b][H+2][W+2][C]
  const float* f; short* fb; int C, H, W, HW, ptiles, c32, blk0;
};
struct ZP {   // zero-fill halo borders of fb
  short* fb; int C, H, W, nb, items, blk0;  // nb = 2*(W+2)+2*H border px/plane
};
struct WtP {  // OIHW 3x3 f32 -> [t][o][i] bf16 (off0 selects branch row block)
  const float* w; short* dst; long CC, MC, off0; int blk0;
};
struct WcP {  // combined 1x1 weights: Wc[64][2C] bf16
  const float* w2b; const float* w3b; short* wc; int csh2, blk0;  // csh2 = log2(2C)
};
struct ConvP {
  const short* fb; const short* wt; const float* bA; const float* bB; short* h;
  int C, H, W, HW, Ng, nb_m, nwg, mfast, blk0;
};
struct DeP {  // MFMA decode: h NHWC [b][p][2C] bf16, wc [64][2C] bf16
  const short* h; const short* wc; const float* bb2; const float* bb3;
  int C2, H, W, b0, loff, ptiles, lvl, blk0; float stride;
};

// ---------------------------------------------------------------------------
// aux: [0,zb_blk0) transpose | [zb_blk0,wt_blk0) halo zero | [wt_blk0,..) wt.
// ---------------------------------------------------------------------------
__global__ __launch_bounds__(256) void aux_mega(TrP T0, TrP T1, TrP T2,
                                                ZP Z0, ZP Z1, ZP Z2,
                                                WtP J0, WtP J1, WtP J2,
                                                WtP J3, WtP J4, WtP J5,
                                                int zb_blk0, int wt_blk0) {
  __shared__ short tile[32][33];
  int bid = blockIdx.x;
  if (bid >= wt_blk0) {
    WtP J = bid >= J5.blk0 ? J5 : bid >= J4.blk0 ? J4 : bid >= J3.blk0 ? J3 :
            bid >= J2.blk0 ? J2 : bid >= J1.blk0 ? J1 : J0;
    long oi = (long)(bid - J.blk0) * 256 + threadIdx.x;
    if (oi >= J.CC) return;
#pragma unroll
    for (int t = 0; t < 9; ++t) J.dst[t * J.MC + J.off0 + oi] = f2bf(J.w[oi * 9 + t]);
    return;
  }
  if (bid >= zb_blk0) {
    ZP Z = bid >= Z2.blk0 ? Z2 : (bid >= Z1.blk0 ? Z1 : Z0);
    int idx = (bid - Z.blk0) * 256 + threadIdx.x;
    if (idx >= Z.items) return;
    const int c8 = Z.C >> 3;
    int ci = idx % c8;
    int rem = idx / c8;
    int b = rem / Z.nb;
    int k = rem - b * Z.nb;
    const int W2 = Z.W + 2;
    int y, x;
    if (k < W2) { y = 0; x = k; }
    else if (k < 2 * W2) { y = Z.H + 1; x = k - W2; }
    else {
      int kk = k - 2 * W2;
      if (kk < Z.H) { y = 1 + kk; x = 0; }
      else { y = 1 + kk - Z.H; x = W2 - 1; }
    }
    short* dst = Z.fb + (((long)b * (Z.H + 2) + y) * W2 + x) * Z.C + ci * 8;
    *(int4*)dst = (int4){0, 0, 0, 0};
    return;
  }
  TrP T = bid >= T2.blk0 ? T2 : (bid >= T1.blk0 ? T1 : T0);
  int l = bid - T.blk0;
  const int pt = l % T.ptiles; l /= T.ptiles;
  const int cg = l % T.c32;
  const int b = l / T.c32;
  const int p0 = pt * 32, c0 = cg * 32, HW = T.HW, C = T.C;
  const int H = T.H, W = T.W;
  const int t = threadIdx.x;
  {
    int cl = t >> 3, pl = (t & 7) * 4;
    int pr = p0 + pl;
    if (pr > HW - 4) pr = HW - 4;
    const float4 v = *(const float4*)(T.f + ((long)b * C + c0 + cl) * HW + pr);
    tile[cl][pl + 0] = f2bf(v.x);
    tile[cl][pl + 1] = f2bf(v.y);
    tile[cl][pl + 2] = f2bf(v.z);
    tile[cl][pl + 3] = f2bf(v.w);
  }
  __syncthreads();
  {
    int pl = t >> 3, cl = (t & 7) * 4;
    int pp = p0 + pl;
    if (pp < HW) {
      int k = pl >> 2;
      int start = p0 + 4 * k;
      if (start > HW - 4) start = HW - 4;
      int col = (start - p0) + (pp - start);
      short4 o;
      o.x = tile[cl + 0][col];
      o.y = tile[cl + 1][col];
      o.z = tile[cl + 2][col];
      o.w = tile[cl + 3][col];
      int y = pp / W, x = pp - y * W;
      *(short4*)(T.fb + (((long)b * (H + 2) + y + 1) * (W + 2) + x + 1) * C + c0 + cl) = o;
    }
  }
}

// ---------------------------------------------------------------------------
// wc_prep: combined 1x1 weight matrix Wc[64][2C] bf16 per level. (proven)
// ---------------------------------------------------------------------------
__global__ __launch_bounds__(256) void wc_prep(WcP K0, WcP K1, WcP K2) {
  int bid = blockIdx.x;
  WcP K = bid >= K2.blk0 ? K2 : (bid >= K1.blk0 ? K1 : K0);
  int idx = (bid - K.blk0) * 256 + threadIdx.x;
  const int C2 = 1 << K.csh2;
  if (idx >= 64 * C2) return;
  const int row = idx >> K.csh2;
  const int c = idx & (C2 - 1);
  const int C = C2 >> 1;
  float v = 0.f;
  if (row < 24) {
    if (c < C) v = K.w2b[row * C + c];
  } else if (row < 51) {
    if (c >= C) v = K.w3b[(row - 24) * C + (c - C)];
  }
  K.wc[idx] = f2bf(v);
}

// ---------------------------------------------------------------------------
// Implicit-GEMM conv3x3, 256x256 tile, BK=64, 512 thr = 8 waves (2M x 4N),
// per-wave C = 128x64 (acc[8][4]). LDS 128 KB: As/Xs[2dbuf][2 k-half][256][32].
// r15 schedule (third 256^2 attempt, derived): each wave reads ONLY its own
// A-half / X-half which stay live the whole K-tile -> no intra-tile barriers.
// ALL 4 half-stages for K-tile t+1 are issued at the TOP of tile t (right
// after the barrier that retired t-1 from the target buffer; race-free), so
// each load ages the full tile (~620cy of MFMA) before the tile-end
// __syncthreads() (vmcnt(0)+barrier) drains it. ONE barrier per K-tile
// (r10 had 8, r12 had 2 with late 1-2-phase-aged stages -> both regressed).
// Staging/swizzle/fragment mapping and epilogue are r12's (refcheck-proven),
// with r14's halo fb (unconditional X staging, no boundary VALU).
// ---------------------------------------------------------------------------
__global__ __launch_bounds__(512, 2) void conv3x3_mega(ConvP P0, ConvP P1, ConvP P2) {
  __shared__ __align__(16) short As[2][2][256 * 32];
  __shared__ __align__(16) short Xs[2][2][256 * 32];

  int bid = blockIdx.x;
  ConvP P = bid >= P2.blk0 ? P2 : (bid >= P1.blk0 ? P1 : P0);
  const int C = P.C, H = P.H, W = P.W, HW = P.HW, Ng = P.Ng;
  const int nb_m = P.nb_m, nwg = P.nwg;
  const int W2 = W + 2;

  // bijective XCD chunk swizzle
  const int orig = bid - P.blk0;
  int wg;
  if (nwg & 7) {
    wg = orig;
  } else {
    const int q = nwg >> 3;
    wg = (orig & 7) * q + (orig >> 3);
  }
  int m, n;
  if (P.mfast) { m = wg % nb_m; n = wg / nb_m; }
  else         { const int nb_n = nwg / nb_m; n = wg % nb_n; m = wg / nb_n; }
  const int mt0 = m * 256;
  const int nt0 = n * 256;
  const int M2 = nb_m * 256;

  const int tid = threadIdx.x;
  const int lane = tid & 63;
  const int wave = tid >> 6;
  const int wm = wave >> 2;   // A row-half (128 rows)
  const int wn = wave & 3;    // X col quarter (64 cols)

  // stage addressing (r12-proven): gload r covers rows r*128+(tid>>2), chunk tid&3
  const int srow0 = tid >> 2;
  const int swzc = ((tid & 3) ^ ((tid >> 3) & 3)) * 8;  // elems within 32-k half
  long xs_base[2], as_base[2];
#pragma unroll
  for (int r = 0; r < 2; ++r) {
    int row = r * 128 + srow0;
    int nn = nt0 + row;
    int nnc = nn < Ng ? nn : 0;  // clamp dead cols to a valid pixel
    int b = nnc / HW; int p = nnc - b * HW;
    int y = p / W;    int x = p - y * W;
    xs_base[r] = (((long)b * (H + 2) + y + 1) * W2 + x + 1) * C + swzc;
    as_base[r] = (long)(mt0 + row) * C + swzc;
  }

  f32x4 acc[8][4];
#pragma unroll
  for (int a_ = 0; a_ < 8; ++a_)
#pragma unroll
    for (int b_ = 0; b_ < 4; ++b_) acc[a_][b_] = (f32x4){0.f, 0.f, 0.f, 0.f};

  const int nkb = C >> 6;
  const int nkt = nkb * 9;
  const long MC = (long)M2 * C;

  // half-tile stagers (2 gload_lds16 each); X unconditional thanks to halo
  auto SA = [&](int db, int kh, const short* wtap, int kb64) {
#pragma unroll
    for (int r = 0; r < 2; ++r)
      gload_lds16(wtap + as_base[r] + kb64 + kh * 32,
                  (char*)&As[db][kh][0] + r * 8192 + tid * 16);
  };
  auto SX = [&](int db, int kh, int doff) {
#pragma unroll
    for (int r = 0; r < 2; ++r)
      gload_lds16(P.fb + xs_base[r] + doff + kh * 32,
                  (char*)&Xs[db][kh][0] + r * 8192 + tid * 16);
  };

  // prologue: K-tile 0 = (kb 0, tap 0: dy=-1,dx=-1)
  {
    const int doff0 = (-W2 - 1) * C;
    SA(0, 0, P.wt, 0);
    SA(0, 1, P.wt, 0);
    SX(0, 0, doff0);
    SX(0, 1, doff0);
    __syncthreads();  // vmcnt(0) + barrier: tile 0 resident
  }

  int ntt = 1, nkb64 = 0;  // (tap, kb*64) of K-tile kt+1
  for (int kt = 0; kt < nkt; ++kt) {
    const int cur = kt & 1;
    const int nxt = cur ^ 1;

    // issue ALL stages for kt+1 NOW (target buffer retired at last barrier;
    // full-tile age before the tile-end drain)
    if (kt + 1 < nkt) {
      const int td3 = ntt / 3;
      const int dyn = td3 - 1, dxn = ntt - td3 * 3 - 1;
      const int doffn = (dyn * W2 + dxn) * C + nkb64;
      const short* wtapn = P.wt + (long)ntt * MC;
      SA(nxt, 0, wtapn, nkb64);
      SA(nxt, 1, wtapn, nkb64);
      SX(nxt, 0, doffn);
      SX(nxt, 1, doffn);
    }

    bf16x8 xf[4];
#pragma unroll
    for (int ph = 0; ph < 4; ++ph) {
      const int ks = ph >> 1, mh = ph & 1;
      const char* Ah = (const char*)&As[cur][ks][0];
      const char* Xh = (const char*)&Xs[cur][ks][0];
      if (mh == 0) {
#pragma unroll
        for (int nf = 0; nf < 4; ++nf) {
          int rl = wn * 64 + nf * 16 + (lane & 15);
          int c = (lane >> 4) ^ ((rl >> 1) & 3);
          xf[nf] = as_bf16x8(*(const int4*)(Xh + rl * 64 + c * 16));
        }
      }
      bf16x8 af[4];
#pragma unroll
      for (int mf = 0; mf < 4; ++mf) {
        int rl = wm * 128 + mh * 64 + mf * 16 + (lane & 15);
        int c = (lane >> 4) ^ ((rl >> 1) & 3);
        af[mf] = as_bf16x8(*(const int4*)(Ah + rl * 64 + c * 16));
      }
      __builtin_amdgcn_s_setprio(1);
#pragma unroll
      for (int mf = 0; mf < 4; ++mf)
#pragma unroll
        for (int nf = 0; nf < 4; ++nf)
          acc[mh * 4 + mf][nf] = __builtin_amdgcn_mfma_f32_16x16x32_bf16(
              af[mf], xf[nf], acc[mh * 4 + mf][nf], 0, 0, 0);
      __builtin_amdgcn_s_setprio(0);
    }
    __syncthreads();  // vmcnt(0)+lgkm+barrier: kt retired, kt+1 resident
    if (++ntt == 9) { ntt = 0; nkb64 += 64; }
  }

  // epilogue (r12-proven): + bias, h NHWC [b][p][M2], short4, N-guarded
  long nbase[4]; int nok[4];
#pragma unroll
  for (int nf = 0; nf < 4; ++nf) {
    int nn = nt0 + wn * 64 + nf * 16 + (lane & 15);
    nok[nf] = nn < Ng;
    int nnc = nok[nf] ? nn : 0;
    int nb = nnc / HW;
    int np = nnc - nb * HW;
    nbase[nf] = ((long)nb * HW + np) * M2;
  }
#pragma unroll
  for (int g = 0; g < 8; ++g) {  // g = mh*4 + mf
    int co0 = mt0 + wm * 128 + (g >> 2) * 64 + (g & 3) * 16 + (lane >> 4) * 4;
    float bv[4];
#pragma unroll
    for (int rg = 0; rg < 4; ++rg) {
      int co = co0 + rg;
      bv[rg] = co < C ? P.bA[co] : P.bB[co - C];
    }
#pragma unroll
    for (int nf = 0; nf < 4; ++nf) {
      if (nok[nf]) {
        short4 o;
        o.x = f2bf(acc[g][nf][0] + bv[0]);
        o.y = f2bf(acc[g][nf][1] + bv[1]);
        o.z = f2bf(acc[g][nf][2] + bv[2]);
        o.w = f2bf(acc[g][nf][3] + bv[3]);
        *(short4*)(P.h + nbase[nf] + co0) = o;
      }
    }
  }
}

// ---------------------------------------------------------------------------
// decode v3 (MFMA, r11-proven): per 32-px tile, G[64][32] = Wc[64][2C] x
// h[2C][32px], K chunked by 128 via LDS (row stride 136 = 2-way alias, free).
// ---------------------------------------------------------------------------
__global__ __launch_bounds__(256) void decode_v3(DeP D0, DeP D1, DeP D2,
                                                 float* __restrict__ out) {
  __shared__ __align__(16) short htileT[32][136];
  __shared__ __align__(16) short Wtile[64][136];
  __shared__ float otile[32][52];
  int bid = blockIdx.x;
  DeP D = bid >= D2.blk0 ? D2 : (bid >= D1.blk0 ? D1 : D0);
  int l = bid - D.blk0;
  const int pt = l % D.ptiles;
  const int bl = l / D.ptiles;
  const int C2 = D.C2, H = D.H, W = D.W, HW = H * W;
  const int t = threadIdx.x;
  const int lane = t & 63;
  const int wv = t >> 6;
  const int p0 = pt * 32;

  const short* hB = D.h + (long)bl * HW * C2;

  f32x4 acc[2];
  acc[0] = (f32x4){0.f, 0.f, 0.f, 0.f};
  acc[1] = (f32x4){0.f, 0.f, 0.f, 0.f};

  const int rounds = C2 >> 7;
  for (int rd = 0; rd < rounds; ++rd) {
    const int c0 = rd << 7;
#pragma unroll
    for (int r = 0; r < 2; ++r) {
      int idx = r * 256 + t;
      int px = idx >> 4, kc = idx & 15;
      int p = p0 + px;
      int pc = p < HW ? p : HW - 1;
      int4 v = *(const int4*)(hB + (long)pc * C2 + c0 + kc * 8);
      *(int4*)&htileT[px][kc * 8] = v;
    }
#pragma unroll
    for (int r = 0; r < 4; ++r) {
      int idx = r * 256 + t;
      int row = idx >> 4, kc = idx & 15;
      int4 v = *(const int4*)(D.wc + (long)row * C2 + c0 + kc * 8);
      *(int4*)&Wtile[row][kc * 8] = v;
    }
    __syncthreads();
#pragma unroll
    for (int st = 0; st < 4; ++st) {
      const int k0 = st * 32 + (lane >> 4) * 8;
      bf16x8 af = as_bf16x8(*(const int4*)&Wtile[wv * 16 + (lane & 15)][k0]);
#pragma unroll
      for (int nf = 0; nf < 2; ++nf) {
        bf16x8 xf = as_bf16x8(*(const int4*)&htileT[nf * 16 + (lane & 15)][k0]);
        acc[nf] = __builtin_amdgcn_mfma_f32_16x16x32_bf16(af, xf, acc[nf], 0, 0, 0);
      }
    }
    __syncthreads();
  }

#pragma unroll
  for (int nf = 0; nf < 2; ++nf) {
    int px = nf * 16 + (lane & 15);
#pragma unroll
    for (int rg = 0; rg < 4; ++rg) {
      int row = wv * 16 + (lane >> 4) * 4 + rg;
      if (row < 51) otile[px][row] = acc[nf][rg];
    }
  }
  __syncthreads();

  if (t < 96) {
    const int pxx = t / 3, a = t - (t / 3) * 3;
    const int p = p0 + pxx;
    if (p < HW) {
      float* o = out + ((size_t)(D.b0 + bl) * TOT_ANCH + D.loff + (size_t)a * HW + p) * 17;
      {
        const int y = p / W, x = p - (p / W) * W;
        float h0 = otile[pxx][a * 8 + 0] + D.bb2[a * 8 + 0];
        float h1 = otile[pxx][a * 8 + 1] + D.bb2[a * 8 + 1];
        float h2 = otile[pxx][a * 8 + 2] + D.bb2[a * 8 + 2];
        float h3 = otile[pxx][a * 8 + 3] + D.bb2[a * 8 + 3];
        float s0 = sig_(h0);
        float s1 = sig_(h1);
        float sw = sig_(h2) * 2.f;
        float sh = sig_(h3) * 2.f;
        o[0] = (s0 * 2.f - 0.5f + (float)x) * D.stride;
        o[1] = (s1 * 2.f - 0.5f + (float)y) * D.stride;
        o[2] = sw * sw * d_anch[D.lvl][a][0];
        o[3] = sh * sh * d_anch[D.lvl][a][1];
        o[4] = sig_(otile[pxx][a * 8 + 4] + D.bb2[a * 8 + 4]);
        o[5] = sig_(otile[pxx][a * 8 + 5] + D.bb2[a * 8 + 5]);
        o[6] = sig_(otile[pxx][a * 8 + 6] + D.bb2[a * 8 + 6]);
        o[7] = sig_(otile[pxx][a * 8 + 7] + D.bb2[a * 8 + 7]);
      }
      {
        float v0 = otile[pxx][24 + a * 9 + 0] + D.bb3[a * 9 + 0];
        float v1 = otile[pxx][24 + a * 9 + 1] + D.bb3[a * 9 + 1];
        float v2 = otile[pxx][24 + a * 9 + 2] + D.bb3[a * 9 + 2];
        float v3 = otile[pxx][24 + a * 9 + 3] + D.bb3[a * 9 + 3];
        float v4 = otile[pxx][24 + a * 9 + 4] + D.bb3[a * 9 + 4];
        float v5 = otile[pxx][24 + a * 9 + 5] + D.bb3[a * 9 + 5];
        float v6 = otile[pxx][24 + a * 9 + 6] + D.bb3[a * 9 + 6];
        float v7 = otile[pxx][24 + a * 9 + 7] + D.bb3[a * 9 + 7];
        float v8 = otile[pxx][24 + a * 9 + 8] + D.bb3[a * 9 + 8];
        float n0 = fmaxf(sqrtf(v2 * v2 + v3 * v3), 1e-12f);
        float n1 = fmaxf(sqrtf(v4 * v4 + v5 * v5), 1e-12f);
        o[8] = v0;
        o[9] = v1;
        o[10] = v2 / n0;
        o[11] = v3 / n0;
        o[12] = v4 / n1;
        o[13] = v5 / n1;
        o[14] = sig_(v6) * 2.f - 1.f;
        o[15] = sig_(v7) * 2.f - 1.f;
        o[16] = sig_(v8) * 2.f - 1.f;
      }
    }
  }
}

// ---------------------------------------------------------------------------

static inline size_t al256(size_t x) { return (x + 255) & ~(size_t)255; }

extern "C" void kernel_launch(void* const* d_in, const int* in_sizes, int n_in,
                              void* d_out, int out_size, void* d_ws, size_t ws_size,
                              hipStream_t stream) {
  (void)in_sizes; (void)n_in; (void)out_size;
  char* ws = (char*)d_ws;
  float* out = (float*)d_out;

  struct Lvl { int C, H, W, loff; float stride; };
  const Lvl L[3] = {{256, 80, 80, 0, 8.f}, {512, 40, 40, 19200, 16.f},
                    {1024, 20, 20, 24000, 32.f}};
  const int B = 8;
  const int ord[3] = {2, 1, 0};  // longest blocks first

  const float* f_[3]; const float *w2a_[3], *b2a_[3], *w2b_[3], *b2b_[3];
  const float *w3a_[3], *b3a_[3], *w3b_[3], *b3b_[3];
  int HW_[3], ptiles_[3], c32_[3], nbm_[3], mfast_[3], csh2_[3], nbrd_[3];
  long CC_[3];
  size_t fbB_[3], wtB_[3], hB_[3], wcB_[3];
  for (int i = 0; i < 3; ++i) {
    f_[i]   = (const float*)d_in[9 * i + 0];
    w2a_[i] = (const float*)d_in[9 * i + 1];
    b2a_[i] = (const float*)d_in[9 * i + 2];
    w2b_[i] = (const float*)d_in[9 * i + 3];
    b2b_[i] = (const float*)d_in[9 * i + 4];
    w3a_[i] = (const float*)d_in[9 * i + 5];
    b3a_[i] = (const float*)d_in[9 * i + 6];
    w3b_[i] = (const float*)d_in[9 * i + 7];
    b3b_[i] = (const float*)d_in[9 * i + 8];
    const int C = L[i].C, H = L[i].H, W = L[i].W;
    HW_[i] = H * W;
    ptiles_[i] = (HW_[i] + 31) / 32;
    c32_[i] = C / 32;
    nbm_[i] = (2 * C) / 256;                           // 256-row M tiles
    CC_[i] = (long)C * C;
    csh2_[i] = (C == 256) ? 9 : (C == 512) ? 10 : 11;  // log2(2C)
    nbrd_[i] = 2 * (W + 2) + 2 * H;                    // border px per plane
    fbB_[i] = (size_t)B * (H + 2) * (W + 2) * C * 2;   // bf16 NHWC + halo
    wtB_[i] = (size_t)36 * CC_[i];                     // 9 * 2C * C bf16
    hB_[i]  = (size_t)B * HW_[i] * 2 * C * 2;          // bf16 NHWC h, M=2C
    wcB_[i] = (size_t)64 * 2 * C * 2;                  // Wc[64][2C] bf16
    mfast_[i] = ((size_t)B * HW_[i] * C >= (size_t)18 * CC_[i]) ? 1 : 0;
  }

  // ---- mega plan ----
  size_t off = 256;
  size_t fb_o[3], wt_o[3], h_o[3], wc_o[3];
  for (int i = 0; i < 3; ++i) { fb_o[i] = off; off += al256(fbB_[i]); }
  for (int i = 0; i < 3; ++i) { wt_o[i] = off; off += al256(wtB_[i]); }
  for (int i = 0; i < 3; ++i) { wc_o[i] = off; off += al256(wcB_[i]); }
  for (int i = 0; i < 3; ++i) { h_o[i] = off; off += al256(hB_[i]); }

  if (off <= ws_size) {
    short* fb[3]; short* wtb[3]; short* hb[3]; short* wcb[3];
    for (int i = 0; i < 3; ++i) {
      fb[i] = (short*)(ws + fb_o[i]);
      wtb[i] = (short*)(ws + wt_o[i]);
      hb[i] = (short*)(ws + h_o[i]);
      wcb[i] = (short*)(ws + wc_o[i]);
    }
    // aux: transpose + halo zero + 3x3 weight transform (one launch)
    TrP T[3]; int tb = 0;
    for (int i = 0; i < 3; ++i) {
      T[i] = TrP{f_[i], fb[i], L[i].C, L[i].H, L[i].W, HW_[i], ptiles_[i], c32_[i], tb};
      tb += ptiles_[i] * c32_[i] * B;
    }
    ZP Z[3]; int zbb = tb;
    for (int i = 0; i < 3; ++i) {
      int items = B * nbrd_[i] * (L[i].C >> 3);
      Z[i] = ZP{fb[i], L[i].C, L[i].H, L[i].W, nbrd_[i], items, zbb};
      zbb += (items + 255) / 256;
    }
    WtP J[6]; int jb = zbb;
    for (int i = 0; i < 3; ++i) {
      J[2 * i]     = WtP{w2a_[i], wtb[i], CC_[i], 2 * CC_[i], 0, jb};
      jb += (int)(CC_[i] / 256);
      J[2 * i + 1] = WtP{w3a_[i], wtb[i], CC_[i], 2 * CC_[i], CC_[i], jb};
      jb += (int)(CC_[i] / 256);
    }
    aux_mega<<<jb, 256, 0, stream>>>(T[0], T[1], T[2], Z[0], Z[1], Z[2],
                                     J[0], J[1], J[2], J[3], J[4], J[5], tb, zbb);
    // wc prep (3 levels)
    WcP K[3]; int kb = 0;
    for (int i = 0; i < 3; ++i) {
      K[i] = WcP{w2b_[i], w3b_[i], wcb[i], csh2_[i], kb};
      kb += (64 * 2 * L[i].C) / 256;
    }
    wc_prep<<<kb, 256, 0, stream>>>(K[0], K[1], K[2]);

    // conv, all levels, longest-first, 256^2 tiles
    ConvP P[3]; int cb = 0;
    for (int k = 0; k < 3; ++k) {
      const int i = ord[k];
      const int Ng = B * HW_[i];
      const int ntn = (Ng + 255) / 256;
      const int nwg = ntn * nbm_[i];
      P[k] = ConvP{fb[i], wtb[i], b2a_[i], b3a_[i], hb[i],
                   L[i].C, L[i].H, L[i].W, HW_[i], Ng, nbm_[i], nwg, mfast_[i], cb};
      cb += nwg;
    }
    conv3x3_mega<<<cb, 512, 0, stream>>>(P[0], P[1], P[2]);

    // decode (MFMA), all levels, longest-first
    DeP D[3]; int db = 0;
    for (int k = 0; k < 3; ++k) {
      const int i = ord[k];
      D[k] = DeP{hb[i], wcb[i], b2b_[i], b3b_[i], 2 * L[i].C, L[i].H, L[i].W,
                 0, L[i].loff, ptiles_[i], i, db, L[i].stride};
      db += ptiles_[i] * B;
    }
    decode_v3<<<db, 256, 0, stream>>>(D[0], D[1], D[2], out);
    return;
  }

  // ---- fallback: per-level passes ----
  for (int i = 0; i < 3; ++i) {
    const int C = L[i].C, H = L[i].H, W = L[i].W, HW = HW_[i];
    int Bg = B;
    for (int cand = 1; cand <= 8; cand <<= 1) {
      int bg = B / cand;
      size_t need = 256 + al256((size_t)bg * (H + 2) * (W + 2) * C * 2) +
                    al256(wtB_[i]) + al256(wcB_[i]) + (size_t)bg * HW * 2 * C * 2;
      if (need <= ws_size) { Bg = bg; break; }
    }
    size_t fo = 256;
    size_t wo = fo + al256((size_t)Bg * (H + 2) * (W + 2) * C * 2);
    size_t co = wo + al256(wtB_[i]);
    size_t ho = co + al256(wcB_[i]);
    short* fb = (short*)(ws + fo);
    short* wtb = (short*)(ws + wo);
    short* wcb = (short*)(ws + co);
    short* hb = (short*)(ws + ho);

    TrP TZ{}; ZP ZZ{}; ZZ.blk0 = INT_MAX;
    WtP J0 = WtP{w2a_[i], wtb, CC_[i], 2 * CC_[i], 0, 0};
    WtP J1 = WtP{w3a_[i], wtb, CC_[i], 2 * CC_[i], CC_[i], (int)(CC_[i] / 256)};
    WtP JX = J1; JX.blk0 = INT_MAX;
    aux_mega<<<(int)(2 * CC_[i] / 256), 256, 0, stream>>>(TZ, TZ, TZ, ZZ, ZZ, ZZ,
                                                          J0, J1, JX, JX, JX, JX, 0, 0);
    WcP K0 = WcP{w2b_[i], w3b_[i], wcb, csh2_[i], 0};
    WcP KX = K0; KX.blk0 = INT_MAX;
    wc_prep<<<(64 * 2 * C) / 256, 256, 0, stream>>>(K0, KX, KX);

    const int nbg = B / Bg;
    for (int g = 0; g < nbg; ++g) {
      const int b0 = g * Bg;
      TrP T0 = TrP{f_[i] + (size_t)b0 * C * HW, fb, C, H, W, HW, ptiles_[i], c32_[i], 0};
      TrP TX = T0; TX.blk0 = INT_MAX;
      int trb = ptiles_[i] * c32_[i] * Bg;
      int items = Bg * nbrd_[i] * (C >> 3);
      ZP Z0 = ZP{fb, C, H, W, nbrd_[i], items, trb};
      ZP ZX = Z0; ZX.blk0 = INT_MAX;
      int zblk = (items + 255) / 256;
      WtP JZ{}; JZ.blk0 = INT_MAX;
      aux_mega<<<trb + zblk, 256, 0, stream>>>(T0, TX, TX, Z0, ZX, ZX, JZ, JZ, JZ,
                                               JZ, JZ, JZ, trb, INT_MAX);

      const int Ng = Bg * HW;
      const int ntn = (Ng + 255) / 256;
      const int nwg = ntn * nbm_[i];
      ConvP Pc = ConvP{fb, wtb, b2a_[i], b3a_[i], hb, C, H, W, HW,
                       Ng, nbm_[i], nwg, mfast_[i], 0};
      ConvP PX = Pc; PX.blk0 = INT_MAX;
      conv3x3_mega<<<nwg, 512, 0, stream>>>(Pc, PX, PX);

      DeP D0 = DeP{hb, wcb, b2b_[i], b3b_[i], 2 * C, H, W,
                   b0, L[i].loff, ptiles_[i], i, 0, L[i].stride};
      DeP DX = D0; DX.blk0 = INT_MAX;
      decode_v3<<<ptiles_[i] * Bg, 256, 0, stream>>>(D0, DX, DX, out);
    }
  }
}

// Round 16
// 413.165 us; speedup vs baseline: 1.0700x; 1.0700x over previous
//
#include <hip/hip_runtime.h>
#include <hip/hip_bf16.h>
#include <cstddef>
#include <cstdint>
#include <climits>

#define TOT_ANCH 25200

typedef __bf16 bf16x8 __attribute__((ext_vector_type(8)));
typedef float f32x4 __attribute__((ext_vector_type(4)));

__device__ __forceinline__ float sig_(float x) { return 1.0f / (1.0f + __expf(-x)); }

__device__ __forceinline__ short f2bf(float v) {
  return (short)__builtin_bit_cast(unsigned short, __float2bfloat16(v));
}
__device__ __forceinline__ float bf2f(short v) {
  unsigned int u = ((unsigned int)(unsigned short)v) << 16;
  return __builtin_bit_cast(float, u);
}
__device__ __forceinline__ bf16x8 as_bf16x8(int4 v) { return __builtin_bit_cast(bf16x8, v); }

__device__ __forceinline__ void gload_lds16(const void* g, void* l) {
  __builtin_amdgcn_global_load_lds((const __attribute__((address_space(1))) void*)g,
                                   (__attribute__((address_space(3))) void*)l, 16, 0, 0);
}

// anchors[level][a][2]
__device__ const float d_anch[3][3][2] = {
    {{10.f, 13.f}, {16.f, 30.f}, {33.f, 23.f}},
    {{30.f, 61.f}, {62.f, 45.f}, {59.f, 119.f}},
    {{116.f, 90.f}, {156.f, 198.f}, {373.f, 326.f}}};

// --------------------------- param structs (by value) -----------------------
struct TrP {  // f32 NCHW -> bf16 NHWC with 1-px halo: fb[b][H+2][W+2][C]
  const float* f; short* fb; int C, H, W, HW, ptiles, c32, blk0;
};
struct ZP {   // zero-fill halo borders of fb
  short* fb; int C, H, W, nb, items, blk0;  // nb = 2*(W+2)+2*H border px/plane
};
struct WtP {  // OIHW 3x3 f32 -> [t][o][i] bf16 (off0 selects branch row block)
  const float* w; short* dst; long CC, MC, off0; int blk0;
};
struct WcP {  // combined 1x1 weights: Wc[64][2C] bf16
  const float* w2b; const float* w3b; short* wc; int csh2, blk0;  // csh2 = log2(2C)
};
struct ConvP {
  const short* fb; const short* wt; const float* bA; const float* bB; short* h;
  int C, H, W, HW, nb_m, nwg, mfast, blk0;
};
struct DeP {  // MFMA decode: h NHWC [b][p][2C] bf16, wc [64][2C] bf16
  const short* h; const short* wc; const float* bb2; const float* bb3;
  int C2, H, W, b0, loff, ptiles, lvl, blk0; float stride;
};

// ---------------------------------------------------------------------------
// aux: [0,zb_blk0) transpose | [zb_blk0,wt_blk0) halo zero | [wt_blk0,..) wt.
// ---------------------------------------------------------------------------
__global__ __launch_bounds__(256) void aux_mega(TrP T0, TrP T1, TrP T2,
                                                ZP Z0, ZP Z1, ZP Z2,
                                                WtP J0, WtP J1, WtP J2,
                                                WtP J3, WtP J4, WtP J5,
                                                int zb_blk0, int wt_blk0) {
  __shared__ short tile[32][33];
  int bid = blockIdx.x;
  if (bid >= wt_blk0) {
    WtP J = bid >= J5.blk0 ? J5 : bid >= J4.blk0 ? J4 : bid >= J3.blk0 ? J3 :
            bid >= J2.blk0 ? J2 : bid >= J1.blk0 ? J1 : J0;
    long oi = (long)(bid - J.blk0) * 256 + threadIdx.x;
    if (oi >= J.CC) return;
#pragma unroll
    for (int t = 0; t < 9; ++t) J.dst[t * J.MC + J.off0 + oi] = f2bf(J.w[oi * 9 + t]);
    return;
  }
  if (bid >= zb_blk0) {
    ZP Z = bid >= Z2.blk0 ? Z2 : (bid >= Z1.blk0 ? Z1 : Z0);
    int idx = (bid - Z.blk0) * 256 + threadIdx.x;
    if (idx >= Z.items) return;
    const int c8 = Z.C >> 3;
    int ci = idx % c8;
    int rem = idx / c8;
    int b = rem / Z.nb;
    int k = rem - b * Z.nb;
    const int W2 = Z.W + 2;
    int y, x;
    if (k < W2) { y = 0; x = k; }
    else if (k < 2 * W2) { y = Z.H + 1; x = k - W2; }
    else {
      int kk = k - 2 * W2;
      if (kk < Z.H) { y = 1 + kk; x = 0; }
      else { y = 1 + kk - Z.H; x = W2 - 1; }
    }
    short* dst = Z.fb + (((long)b * (Z.H + 2) + y) * W2 + x) * Z.C + ci * 8;
    *(int4*)dst = (int4){0, 0, 0, 0};
    return;
  }
  TrP T = bid >= T2.blk0 ? T2 : (bid >= T1.blk0 ? T1 : T0);
  int l = bid - T.blk0;
  const int pt = l % T.ptiles; l /= T.ptiles;
  const int cg = l % T.c32;
  const int b = l / T.c32;
  const int p0 = pt * 32, c0 = cg * 32, HW = T.HW, C = T.C;
  const int H = T.H, W = T.W;
  const int t = threadIdx.x;
  {
    int cl = t >> 3, pl = (t & 7) * 4;
    int pr = p0 + pl;
    if (pr > HW - 4) pr = HW - 4;
    const float4 v = *(const float4*)(T.f + ((long)b * C + c0 + cl) * HW + pr);
    tile[cl][pl + 0] = f2bf(v.x);
    tile[cl][pl + 1] = f2bf(v.y);
    tile[cl][pl + 2] = f2bf(v.z);
    tile[cl][pl + 3] = f2bf(v.w);
  }
  __syncthreads();
  {
    int pl = t >> 3, cl = (t & 7) * 4;
    int pp = p0 + pl;
    if (pp < HW) {
      int k = pl >> 2;
      int start = p0 + 4 * k;
      if (start > HW - 4) start = HW - 4;
      int col = (start - p0) + (pp - start);
      short4 o;
      o.x = tile[cl + 0][col];
      o.y = tile[cl + 1][col];
      o.z = tile[cl + 2][col];
      o.w = tile[cl + 3][col];
      int y = pp / W, x = pp - y * W;
      *(short4*)(T.fb + (((long)b * (H + 2) + y + 1) * (W + 2) + x + 1) * C + c0 + cl) = o;
    }
  }
}

// ---------------------------------------------------------------------------
// wc_prep: combined 1x1 weight matrix Wc[64][2C] bf16 per level. (proven)
// ---------------------------------------------------------------------------
__global__ __launch_bounds__(256) void wc_prep(WcP K0, WcP K1, WcP K2) {
  int bid = blockIdx.x;
  WcP K = bid >= K2.blk0 ? K2 : (bid >= K1.blk0 ? K1 : K0);
  int idx = (bid - K.blk0) * 256 + threadIdx.x;
  const int C2 = 1 << K.csh2;
  if (idx >= 64 * C2) return;
  const int row = idx >> K.csh2;
  const int c = idx & (C2 - 1);
  const int C = C2 >> 1;
  float v = 0.f;
  if (row < 24) {
    if (c < C) v = K.w2b[row * C + c];
  } else if (row < 51) {
    if (c >= C) v = K.w3b[(row - 24) * C + (c - C)];
  }
  K.wc[idx] = f2bf(v);
}

// ---------------------------------------------------------------------------
// Implicit-GEMM conv3x3 (r14-proven, FINAL): 128x128 tile, BK=64, 4 waves,
// 32 KB LDS single-buffer, kb OUTER / tap INNER, 2 barriers/step,
// global_load_lds width-16, XOR chunk swizzle via pre-swizzled global source,
// bijective XCD swizzle, longest level first, setprio around MFMA.
// fb is [b][H+2][W+2][C] with zeroed halo -> X staging is UNCONDITIONAL.
// Epilogue: h NHWC packed short4. Measured 348 us / MfmaUtil 50% / 1046 TF.
// NOTE: 256^2 deep-pipeline attempts (r10/r12/r15: 34/35.5/38.7% MfmaUtil)
// all lost to this structure's 3-blocks/CU cross-block latency hiding.
// ---------------------------------------------------------------------------
__global__ __launch_bounds__(256, 3) void conv3x3_mega(ConvP P0, ConvP P1, ConvP P2) {
  __shared__ __align__(16) short As[128 * 64];
  __shared__ __align__(16) short Xs[128 * 64];

  int bid = blockIdx.x;
  ConvP P = bid >= P2.blk0 ? P2 : (bid >= P1.blk0 ? P1 : P0);
  const int C = P.C, H = P.H, W = P.W, HW = P.HW, nb_m = P.nb_m, nwg = P.nwg;
  const int W2 = W + 2;

  const int orig = bid - P.blk0;
  const int q = nwg >> 3, rr = nwg & 7;
  const int xcd = orig & 7;
  const int wg = (xcd < rr ? xcd * (q + 1) : rr * (q + 1) + (xcd - rr) * q) + (orig >> 3);
  int m, n;
  if (P.mfast) { m = wg % nb_m; n = wg / nb_m; }
  else         { const int nb_n = nwg / nb_m; n = wg % nb_n; m = wg / nb_n; }
  const int mt0 = m * 128;
  const int nt0 = n * 128;
  const int M2 = nb_m * 128;

  const int tid = threadIdx.x;
  const int lane = tid & 63;
  const int wave = tid >> 6;
  const int wm = (wave >> 1) * 64;
  const int wn = (wave & 1) * 64;
  const int s = tid & 7;

  long xs_base[4];
  long as_base[4];
#pragma unroll
  for (int r = 0; r < 4; ++r) {
    int cl = r * 32 + (tid >> 3);
    int nn = nt0 + cl;
    int b = nn / HW; int p = nn - b * HW;
    int y = p / W;  int x = p - y * W;
    int swz = (s ^ (cl & 7)) * 8;
    xs_base[r] = (((long)b * (H + 2) + y + 1) * W2 + x + 1) * C + swz;
    as_base[r] = (long)(mt0 + cl) * C + swz;
  }

  f32x4 acc[4][4];
#pragma unroll
  for (int a_ = 0; a_ < 4; ++a_)
#pragma unroll
    for (int b_ = 0; b_ < 4; ++b_) acc[a_][b_] = (f32x4){0.f, 0.f, 0.f, 0.f};

  const int nkb = C >> 6;
  const long MC = (long)M2 * C;

  for (int kb = 0; kb < nkb; ++kb) {
    const int kb64 = kb << 6;
    for (int t = 0; t < 9; ++t) {
      const int dy = t / 3 - 1, dx = t - (t / 3) * 3 - 1;
      // lane-uniform tap offsets -> SGPR; per-lane bases precomputed
      const short* gxp = P.fb + (dy * W2 + dx) * C + kb64;
      const short* gap = P.wt + (long)t * MC + kb64;
#pragma unroll
      for (int r = 0; r < 4; ++r) {
        gload_lds16(gap + as_base[r], (char*)As + r * 4096 + tid * 16);
        gload_lds16(gxp + xs_base[r], (char*)Xs + r * 4096 + tid * 16);
      }
      __syncthreads();

#pragma unroll
      for (int ks = 0; ks < 2; ++ks) {
        bf16x8 af[4], xf[4];
#pragma unroll
        for (int mf = 0; mf < 4; ++mf) {
          int row = wm + mf * 16 + (lane & 15);
          int c = (ks * 4 + (lane >> 4)) ^ (row & 7);
          af[mf] = as_bf16x8(*(const int4*)((const char*)As + row * 128 + c * 16));
        }
#pragma unroll
        for (int nf = 0; nf < 4; ++nf) {
          int col = wn + nf * 16 + (lane & 15);
          int c = (ks * 4 + (lane >> 4)) ^ (col & 7);
          xf[nf] = as_bf16x8(*(const int4*)((const char*)Xs + col * 128 + c * 16));
        }
        __builtin_amdgcn_s_setprio(1);
#pragma unroll
        for (int mf = 0; mf < 4; ++mf)
#pragma unroll
          for (int nf = 0; nf < 4; ++nf)
            acc[mf][nf] = __builtin_amdgcn_mfma_f32_16x16x32_bf16(af[mf], xf[nf],
                                                                  acc[mf][nf], 0, 0, 0);
        __builtin_amdgcn_s_setprio(0);
      }
      __syncthreads();
    }
  }

  // epilogue: + bias, store h NHWC [b][p][M2] bf16 with packed short4 stores
  long nbase[4];
#pragma unroll
  for (int nf = 0; nf < 4; ++nf) {
    int nn = nt0 + wn + nf * 16 + (lane & 15);
    int nb = nn / HW;
    int np = nn - nb * HW;
    nbase[nf] = ((long)nb * HW + np) * M2;
  }
#pragma unroll
  for (int mf = 0; mf < 4; ++mf) {
    int co0 = mt0 + wm + mf * 16 + (lane >> 4) * 4;
    float bv[4];
#pragma unroll
    for (int rg = 0; rg < 4; ++rg) {
      int co = co0 + rg;
      bv[rg] = co < C ? P.bA[co] : P.bB[co - C];
    }
#pragma unroll
    for (int nf = 0; nf < 4; ++nf) {
      short4 o;
      o.x = f2bf(acc[mf][nf][0] + bv[0]);
      o.y = f2bf(acc[mf][nf][1] + bv[1]);
      o.z = f2bf(acc[mf][nf][2] + bv[2]);
      o.w = f2bf(acc[mf][nf][3] + bv[3]);
      *(short4*)(P.h + nbase[nf] + co0) = o;
    }
  }
}

// ---------------------------------------------------------------------------
// decode v3 (MFMA, r11-proven): per 32-px tile, G[64][32] = Wc[64][2C] x
// h[2C][32px], K chunked by 128 via LDS (row stride 136 = 2-way alias, free).
// ---------------------------------------------------------------------------
__global__ __launch_bounds__(256) void decode_v3(DeP D0, DeP D1, DeP D2,
                                                 float* __restrict__ out) {
  __shared__ __align__(16) short htileT[32][136];
  __shared__ __align__(16) short Wtile[64][136];
  __shared__ float otile[32][52];
  int bid = blockIdx.x;
  DeP D = bid >= D2.blk0 ? D2 : (bid >= D1.blk0 ? D1 : D0);
  int l = bid - D.blk0;
  const int pt = l % D.ptiles;
  const int bl = l / D.ptiles;
  const int C2 = D.C2, H = D.H, W = D.W, HW = H * W;
  const int t = threadIdx.x;
  const int lane = t & 63;
  const int wv = t >> 6;
  const int p0 = pt * 32;

  const short* hB = D.h + (long)bl * HW * C2;

  f32x4 acc[2];
  acc[0] = (f32x4){0.f, 0.f, 0.f, 0.f};
  acc[1] = (f32x4){0.f, 0.f, 0.f, 0.f};

  const int rounds = C2 >> 7;
  for (int rd = 0; rd < rounds; ++rd) {
    const int c0 = rd << 7;
#pragma unroll
    for (int r = 0; r < 2; ++r) {
      int idx = r * 256 + t;
      int px = idx >> 4, kc = idx & 15;
      int p = p0 + px;
      int pc = p < HW ? p : HW - 1;
      int4 v = *(const int4*)(hB + (long)pc * C2 + c0 + kc * 8);
      *(int4*)&htileT[px][kc * 8] = v;
    }
#pragma unroll
    for (int r = 0; r < 4; ++r) {
      int idx = r * 256 + t;
      int row = idx >> 4, kc = idx & 15;
      int4 v = *(const int4*)(D.wc + (long)row * C2 + c0 + kc * 8);
      *(int4*)&Wtile[row][kc * 8] = v;
    }
    __syncthreads();
#pragma unroll
    for (int st = 0; st < 4; ++st) {
      const int k0 = st * 32 + (lane >> 4) * 8;
      bf16x8 af = as_bf16x8(*(const int4*)&Wtile[wv * 16 + (lane & 15)][k0]);
#pragma unroll
      for (int nf = 0; nf < 2; ++nf) {
        bf16x8 xf = as_bf16x8(*(const int4*)&htileT[nf * 16 + (lane & 15)][k0]);
        acc[nf] = __builtin_amdgcn_mfma_f32_16x16x32_bf16(af, xf, acc[nf], 0, 0, 0);
      }
    }
    __syncthreads();
  }

#pragma unroll
  for (int nf = 0; nf < 2; ++nf) {
    int px = nf * 16 + (lane & 15);
#pragma unroll
    for (int rg = 0; rg < 4; ++rg) {
      int row = wv * 16 + (lane >> 4) * 4 + rg;
      if (row < 51) otile[px][row] = acc[nf][rg];
    }
  }
  __syncthreads();

  if (t < 96) {
    const int pxx = t / 3, a = t - (t / 3) * 3;
    const int p = p0 + pxx;
    if (p < HW) {
      float* o = out + ((size_t)(D.b0 + bl) * TOT_ANCH + D.loff + (size_t)a * HW + p) * 17;
      {
        const int y = p / W, x = p - (p / W) * W;
        float h0 = otile[pxx][a * 8 + 0] + D.bb2[a * 8 + 0];
        float h1 = otile[pxx][a * 8 + 1] + D.bb2[a * 8 + 1];
        float h2 = otile[pxx][a * 8 + 2] + D.bb2[a * 8 + 2];
        float h3 = otile[pxx][a * 8 + 3] + D.bb2[a * 8 + 3];
        float s0 = sig_(h0);
        float s1 = sig_(h1);
        float sw = sig_(h2) * 2.f;
        float sh = sig_(h3) * 2.f;
        o[0] = (s0 * 2.f - 0.5f + (float)x) * D.stride;
        o[1] = (s1 * 2.f - 0.5f + (float)y) * D.stride;
        o[2] = sw * sw * d_anch[D.lvl][a][0];
        o[3] = sh * sh * d_anch[D.lvl][a][1];
        o[4] = sig_(otile[pxx][a * 8 + 4] + D.bb2[a * 8 + 4]);
        o[5] = sig_(otile[pxx][a * 8 + 5] + D.bb2[a * 8 + 5]);
        o[6] = sig_(otile[pxx][a * 8 + 6] + D.bb2[a * 8 + 6]);
        o[7] = sig_(otile[pxx][a * 8 + 7] + D.bb2[a * 8 + 7]);
      }
      {
        float v0 = otile[pxx][24 + a * 9 + 0] + D.bb3[a * 9 + 0];
        float v1 = otile[pxx][24 + a * 9 + 1] + D.bb3[a * 9 + 1];
        float v2 = otile[pxx][24 + a * 9 + 2] + D.bb3[a * 9 + 2];
        float v3 = otile[pxx][24 + a * 9 + 3] + D.bb3[a * 9 + 3];
        float v4 = otile[pxx][24 + a * 9 + 4] + D.bb3[a * 9 + 4];
        float v5 = otile[pxx][24 + a * 9 + 5] + D.bb3[a * 9 + 5];
        float v6 = otile[pxx][24 + a * 9 + 6] + D.bb3[a * 9 + 6];
        float v7 = otile[pxx][24 + a * 9 + 7] + D.bb3[a * 9 + 7];
        float v8 = otile[pxx][24 + a * 9 + 8] + D.bb3[a * 9 + 8];
        float n0 = fmaxf(sqrtf(v2 * v2 + v3 * v3), 1e-12f);
        float n1 = fmaxf(sqrtf(v4 * v4 + v5 * v5), 1e-12f);
        o[8] = v0;
        o[9] = v1;
        o[10] = v2 / n0;
        o[11] = v3 / n0;
        o[12] = v4 / n1;
        o[13] = v5 / n1;
        o[14] = sig_(v6) * 2.f - 1.f;
        o[15] = sig_(v7) * 2.f - 1.f;
        o[16] = sig_(v8) * 2.f - 1.f;
      }
    }
  }
}

// ---------------------------------------------------------------------------

static inline size_t al256(size_t x) { return (x + 255) & ~(size_t)255; }

extern "C" void kernel_launch(void* const* d_in, const int* in_sizes, int n_in,
                              void* d_out, int out_size, void* d_ws, size_t ws_size,
                              hipStream_t stream) {
  (void)in_sizes; (void)n_in; (void)out_size;
  char* ws = (char*)d_ws;
  float* out = (float*)d_out;

  struct Lvl { int C, H, W, loff; float stride; };
  const Lvl L[3] = {{256, 80, 80, 0, 8.f}, {512, 40, 40, 19200, 16.f},
                    {1024, 20, 20, 24000, 32.f}};
  const int B = 8;
  const int ord[3] = {2, 1, 0};  // longest blocks first

  const float* f_[3]; const float *w2a_[3], *b2a_[3], *w2b_[3], *b2b_[3];
  const float *w3a_[3], *b3a_[3], *w3b_[3], *b3b_[3];
  int HW_[3], ptiles_[3], c32_[3], nbm_[3], mfast_[3], csh2_[3], nbrd_[3];
  long CC_[3];
  size_t fbB_[3], wtB_[3], hB_[3], wcB_[3];
  for (int i = 0; i < 3; ++i) {
    f_[i]   = (const float*)d_in[9 * i + 0];
    w2a_[i] = (const float*)d_in[9 * i + 1];
    b2a_[i] = (const float*)d_in[9 * i + 2];
    w2b_[i] = (const float*)d_in[9 * i + 3];
    b2b_[i] = (const float*)d_in[9 * i + 4];
    w3a_[i] = (const float*)d_in[9 * i + 5];
    b3a_[i] = (const float*)d_in[9 * i + 6];
    w3b_[i] = (const float*)d_in[9 * i + 7];
    b3b_[i] = (const float*)d_in[9 * i + 8];
    const int C = L[i].C, H = L[i].H, W = L[i].W;
    HW_[i] = H * W;
    ptiles_[i] = (HW_[i] + 31) / 32;
    c32_[i] = C / 32;
    nbm_[i] = (2 * C) / 128;
    CC_[i] = (long)C * C;
    csh2_[i] = (C == 256) ? 9 : (C == 512) ? 10 : 11;  // log2(2C)
    nbrd_[i] = 2 * (W + 2) + 2 * H;                    // border px per plane
    fbB_[i] = (size_t)B * (H + 2) * (W + 2) * C * 2;   // bf16 NHWC + halo
    wtB_[i] = (size_t)36 * CC_[i];                     // 9 * 2C * C bf16
    hB_[i]  = (size_t)B * HW_[i] * 2 * C * 2;          // bf16 NHWC h, M=2C
    wcB_[i] = (size_t)64 * 2 * C * 2;                  // Wc[64][2C] bf16
    mfast_[i] = ((size_t)B * HW_[i] * C >= (size_t)18 * CC_[i]) ? 1 : 0;
  }

  // ---- mega plan ----
  size_t off = 256;
  size_t fb_o[3], wt_o[3], h_o[3], wc_o[3];
  for (int i = 0; i < 3; ++i) { fb_o[i] = off; off += al256(fbB_[i]); }
  for (int i = 0; i < 3; ++i) { wt_o[i] = off; off += al256(wtB_[i]); }
  for (int i = 0; i < 3; ++i) { wc_o[i] = off; off += al256(wcB_[i]); }
  for (int i = 0; i < 3; ++i) { h_o[i] = off; off += al256(hB_[i]); }

  if (off <= ws_size) {
    short* fb[3]; short* wtb[3]; short* hb[3]; short* wcb[3];
    for (int i = 0; i < 3; ++i) {
      fb[i] = (short*)(ws + fb_o[i]);
      wtb[i] = (short*)(ws + wt_o[i]);
      hb[i] = (short*)(ws + h_o[i]);
      wcb[i] = (short*)(ws + wc_o[i]);
    }
    // aux: transpose + halo zero + 3x3 weight transform (one launch)
    TrP T[3]; int tb = 0;
    for (int i = 0; i < 3; ++i) {
      T[i] = TrP{f_[i], fb[i], L[i].C, L[i].H, L[i].W, HW_[i], ptiles_[i], c32_[i], tb};
      tb += ptiles_[i] * c32_[i] * B;
    }
    ZP Z[3]; int zbb = tb;
    for (int i = 0; i < 3; ++i) {
      int items = B * nbrd_[i] * (L[i].C >> 3);
      Z[i] = ZP{fb[i], L[i].C, L[i].H, L[i].W, nbrd_[i], items, zbb};
      zbb += (items + 255) / 256;
    }
    WtP J[6]; int jb = zbb;
    for (int i = 0; i < 3; ++i) {
      J[2 * i]     = WtP{w2a_[i], wtb[i], CC_[i], 2 * CC_[i], 0, jb};
      jb += (int)(CC_[i] / 256);
      J[2 * i + 1] = WtP{w3a_[i], wtb[i], CC_[i], 2 * CC_[i], CC_[i], jb};
      jb += (int)(CC_[i] / 256);
    }
    aux_mega<<<jb, 256, 0, stream>>>(T[0], T[1], T[2], Z[0], Z[1], Z[2],
                                     J[0], J[1], J[2], J[3], J[4], J[5], tb, zbb);
    // wc prep (3 levels)
    WcP K[3]; int kb = 0;
    for (int i = 0; i < 3; ++i) {
      K[i] = WcP{w2b_[i], w3b_[i], wcb[i], csh2_[i], kb};
      kb += (64 * 2 * L[i].C) / 256;
    }
    wc_prep<<<kb, 256, 0, stream>>>(K[0], K[1], K[2]);

    // conv, all levels, longest-first
    ConvP P[3]; int cb = 0;
    for (int k = 0; k < 3; ++k) {
      const int i = ord[k];
      int nwg = (B * HW_[i] / 128) * nbm_[i];
      P[k] = ConvP{fb[i], wtb[i], b2a_[i], b3a_[i], hb[i],
                   L[i].C, L[i].H, L[i].W, HW_[i], nbm_[i], nwg, mfast_[i], cb};
      cb += nwg;
    }
    conv3x3_mega<<<cb, 256, 0, stream>>>(P[0], P[1], P[2]);

    // decode (MFMA), all levels, longest-first
    DeP D[3]; int db = 0;
    for (int k = 0; k < 3; ++k) {
      const int i = ord[k];
      D[k] = DeP{hb[i], wcb[i], b2b_[i], b3b_[i], 2 * L[i].C, L[i].H, L[i].W,
                 0, L[i].loff, ptiles_[i], i, db, L[i].stride};
      db += ptiles_[i] * B;
    }
    decode_v3<<<db, 256, 0, stream>>>(D[0], D[1], D[2], out);
    return;
  }

  // ---- fallback: per-level passes ----
  for (int i = 0; i < 3; ++i) {
    const int C = L[i].C, H = L[i].H, W = L[i].W, HW = HW_[i];
    int Bg = B;
    for (int cand = 1; cand <= 8; cand <<= 1) {
      int bg = B / cand;
      if (((long)bg * HW) % 128) continue;
      size_t need = 256 + al256((size_t)bg * (H + 2) * (W + 2) * C * 2) +
                    al256(wtB_[i]) + al256(wcB_[i]) + (size_t)bg * HW * 2 * C * 2;
      if (need <= ws_size) { Bg = bg; break; }
    }
    size_t fo = 256;
    size_t wo = fo + al256((size_t)Bg * (H + 2) * (W + 2) * C * 2);
    size_t co = wo + al256(wtB_[i]);
    size_t ho = co + al256(wcB_[i]);
    short* fb = (short*)(ws + fo);
    short* wtb = (short*)(ws + wo);
    short* wcb = (short*)(ws + co);
    short* hb = (short*)(ws + ho);

    // weight transforms once per level
    TrP TZ{}; ZP ZZ{}; ZZ.blk0 = INT_MAX;
    WtP J0 = WtP{w2a_[i], wtb, CC_[i], 2 * CC_[i], 0, 0};
    WtP J1 = WtP{w3a_[i], wtb, CC_[i], 2 * CC_[i], CC_[i], (int)(CC_[i] / 256)};
    WtP JX = J1; JX.blk0 = INT_MAX;
    aux_mega<<<(int)(2 * CC_[i] / 256), 256, 0, stream>>>(TZ, TZ, TZ, ZZ, ZZ, ZZ,
                                                          J0, J1, JX, JX, JX, JX, 0, 0);
    WcP K0 = WcP{w2b_[i], w3b_[i], wcb, csh2_[i], 0};
    WcP KX = K0; KX.blk0 = INT_MAX;
    wc_prep<<<(64 * 2 * C) / 256, 256, 0, stream>>>(K0, KX, KX);

    const int nbg = B / Bg;
    for (int g = 0; g < nbg; ++g) {
      const int b0 = g * Bg;
      // transpose + halo zero for this group
      TrP T0 = TrP{f_[i] + (size_t)b0 * C * HW, fb, C, H, W, HW, ptiles_[i], c32_[i], 0};
      TrP TX = T0; TX.blk0 = INT_MAX;
      int trb = ptiles_[i] * c32_[i] * Bg;
      int items = Bg * nbrd_[i] * (C >> 3);
      ZP Z0 = ZP{fb, C, H, W, nbrd_[i], items, trb};
      ZP ZX = Z0; ZX.blk0 = INT_MAX;
      int zblk = (items + 255) / 256;
      WtP JZ{}; JZ.blk0 = INT_MAX;
      aux_mega<<<trb + zblk, 256, 0, stream>>>(T0, TX, TX, Z0, ZX, ZX, JZ, JZ, JZ,
                                               JZ, JZ, JZ, trb, INT_MAX);

      int nwg = (Bg * HW / 128) * nbm_[i];
      ConvP Pc = ConvP{fb, wtb, b2a_[i], b3a_[i], hb, C, H, W, HW,
                       nbm_[i], nwg, mfast_[i], 0};
      ConvP PX = Pc; PX.blk0 = INT_MAX;
      conv3x3_mega<<<nwg, 256, 0, stream>>>(Pc, PX, PX);

      DeP D0 = DeP{hb, wcb, b2b_[i], b3b_[i], 2 * C, H, W,
                   b0, L[i].loff, ptiles_[i], i, 0, L[i].stride};
      DeP DX = D0; DX.blk0 = INT_MAX;
      decode_v3<<<ptiles_[i] * Bg, 256, 0, stream>>>(D0, DX, DX, out);
    }
  }
}